// Round 1
// baseline (33.183 us; speedup 1.0000x reference)
//
#include <hip/hip_runtime.h>
#include <hip/hip_bf16.h>

typedef __attribute__((ext_vector_type(8))) short short8;
typedef __attribute__((ext_vector_type(4))) float f32x4;

#define C_COUPLING 1.0f
#define C_DT 1.0f
#define C_ATTR 1.0f

// float -> bf16 bits (round-to-nearest via +0x8000; inputs are finite, |v|<=~1)
__device__ __forceinline__ short f2bf(float f) {
  unsigned u = __builtin_bit_cast(unsigned, f);
  return (short)((u + 0x8000u) >> 16);
}

__global__ __launch_bounds__(256) void vk_init(const float* __restrict__ th,
                                               const float* __restrict__ ga,
                                               float* __restrict__ out, int n) {
  int i = blockIdx.x * blockDim.x + threadIdx.x;
  if (i < n) {
    float t = th[i];
    out[i] = t + C_DT * (C_ATTR * (ga[i] - t));
  }
}

// Each wave owns one 16-row i-tile of batch b and a j-chunk.
// P = (A.*cos(alpha)) x [sin(theta)|cos(theta)]  (cols 0-7 = s-part, 8-15 = c-part)
// Q = (A.*sin(alpha)) x [sin(theta)|cos(theta)]
// coupling(i,d) = (C/N) * ( c_i*(P[d] - Q[d+8]) - s_i*(P[d+8] + Q[d]) )
__global__ __launch_bounds__(256) void vk_main(
    const float* __restrict__ theta,
    const float* __restrict__ affinity,
    const float* __restrict__ alpha,
    float* __restrict__ out,
    int N, int jsCnt, int jChunk) {
  const int jc = blockIdx.x % jsCnt;
  int t = blockIdx.x / jsCnt;
  const int nib = N >> 6;            // i-blocks of 64 rows
  const int ib = t % nib;
  const int b = t / nib;

  const int wave = threadIdx.x >> 6;
  const int lane = threadIdx.x & 63;
  const int itile = ib * 4 + wave;   // 16-row tile
  const int g = lane >> 4;           // k-group 0..3
  const int col = lane & 15;         // A row (M) / B col (N) index
  const int arow = itile * 16 + col;
  const int d = col & 7;

  const float* __restrict__ Arow = affinity + ((size_t)b * N + arow) * (size_t)N;
  const float* __restrict__ Lrow = alpha    + ((size_t)b * N + arow) * (size_t)N;

  // cols 0-7 take sin(theta), cols 8-15 take cos(theta) = sin(theta + pi/2)
  const float bphase = (col < 8) ? 0.0f : 1.57079632679f;

  f32x4 P = {0.f, 0.f, 0.f, 0.f};
  f32x4 Q = {0.f, 0.f, 0.f, 0.f};

  const int j0 = jc * jChunk;
  const int j1 = j0 + jChunk;
  #pragma unroll 2
  for (int jt = j0; jt < j1; jt += 32) {
    const int jl = jt + g * 8;       // this lane's 8 consecutive j's
    const float4 a0 = *(const float4*)(Arow + jl);
    const float4 a1 = *(const float4*)(Arow + jl + 4);
    const float4 l0 = *(const float4*)(Lrow + jl);
    const float4 l1 = *(const float4*)(Lrow + jl + 4);
    const float* tp = theta + (((size_t)b * N + jl) << 3) + d;

    short8 bf, wc, ws;
    #pragma unroll
    for (int k = 0; k < 8; ++k) {
      float thj = tp[(size_t)k * 8];
      bf[k] = f2bf(__sinf(thj + bphase));
    }
    const float av[8] = {a0.x, a0.y, a0.z, a0.w, a1.x, a1.y, a1.z, a1.w};
    const float lv[8] = {l0.x, l0.y, l0.z, l0.w, l1.x, l1.y, l1.z, l1.w};
    #pragma unroll
    for (int k = 0; k < 8; ++k) {
      float sv = __sinf(lv[k]);
      float cv = __cosf(lv[k]);
      wc[k] = f2bf(av[k] * cv);
      ws[k] = f2bf(av[k] * sv);
    }
    P = __builtin_amdgcn_mfma_f32_16x16x32_bf16(wc, bf, P, 0, 0, 0);
    Q = __builtin_amdgcn_mfma_f32_16x16x32_bf16(ws, bf, Q, 0, 0, 0);
  }

  // C/D layout: col = lane&15, row = (lane>>4)*4 + reg  [m89]
  // lane col=d needs cols d+8 values -> partner lane = lane ^ 8 (same g, same rows)
  float pc[4], qc[4];
  #pragma unroll
  for (int r = 0; r < 4; ++r) {
    pc[r] = __shfl_xor(P[r], 8, 64);
    qc[r] = __shfl_xor(Q[r], 8, 64);
  }
  if (col < 8) {
    const float sc = C_COUPLING / (float)N;
    #pragma unroll
    for (int r = 0; r < 4; ++r) {
      const int i = itile * 16 + g * 4 + r;
      const size_t oi = (((size_t)b * N + i) << 3) + col;
      const float thi = theta[oi];
      const float sv = __sinf(thi);
      const float cv = __cosf(thi);
      const float coup = sc * (cv * (P[r] - qc[r]) - sv * (pc[r] + Q[r]));
      unsafeAtomicAdd(out + oi, coup);
    }
  }
}

extern "C" void kernel_launch(void* const* d_in, const int* in_sizes, int n_in,
                              void* d_out, int out_size, void* d_ws, size_t ws_size,
                              hipStream_t stream) {
  const float* theta = (const float*)d_in[0];
  const float* gamma = (const float*)d_in[1];
  const float* aff   = (const float*)d_in[2];
  const float* alp   = (const float*)d_in[3];
  float* out = (float*)d_out;

  const long t0 = in_sizes[0];              // B*N*D (D=8)
  const long t2 = in_sizes[2];              // B*N*N
  const int N = (int)(8 * t2 / t0);
  const int B = (int)(t0 / ((long)N * 8));

  const int n = B * N * 8;
  vk_init<<<dim3((n + 255) / 256), dim3(256), 0, stream>>>(theta, gamma, out, n);

  const int js = 8;                          // j-split for occupancy: 1024 blocks
  const int jChunk = N / js;
  dim3 grid(B * (N / 64) * js);
  vk_main<<<grid, dim3(256), 0, stream>>>(theta, aff, alp, out, N, js, jChunk);
}

// Round 2
// 32.147 us; speedup vs baseline: 1.0322x; 1.0322x over previous
//
#include <hip/hip_runtime.h>
#include <hip/hip_bf16.h>

typedef __attribute__((ext_vector_type(8))) short short8;
typedef __attribute__((ext_vector_type(4))) float f32x4;

#define C_COUPLING 1.0f
#define C_DT 1.0f
#define C_ATTR 1.0f

// float -> bf16 bits (round-to-nearest-ish via +0x8000; inputs finite, |v|<=1)
__device__ __forceinline__ short f2bf(float f) {
  unsigned u = __builtin_bit_cast(unsigned, f);
  return (short)((u + 0x8000u) >> 16);
}

// Fused prologue (tiny): out = theta + DT*ATTR*(gamma-theta), and build the
// bf16 trig table T[b][c][j] = sin(theta[b,j,c&7] + (c<8 ? 0 : pi/2)),
// i.e. rows 0-7 = sin(theta[.,.,d]), rows 8-15 = cos(theta[.,.,d]).
// One thread per (b,j). T row-major in j -> consecutive threads write
// consecutive 2B addresses per row (coalesced); 256 KB total, L2-resident.
__global__ __launch_bounds__(256) void vk_prep(
    const float* __restrict__ th, const float* __restrict__ ga,
    float* __restrict__ out, unsigned short* __restrict__ T,
    int N, int total) {
  int idx = blockIdx.x * blockDim.x + threadIdx.x;   // b*N + j
  if (idx >= total) return;
  const int b = idx / N, j = idx - b * N;
  const float4 t0 = *(const float4*)(th + (size_t)idx * 8);
  const float4 t1 = *(const float4*)(th + (size_t)idx * 8 + 4);
  const float4 g0 = *(const float4*)(ga + (size_t)idx * 8);
  const float4 g1 = *(const float4*)(ga + (size_t)idx * 8 + 4);
  float4 o0, o1;
  o0.x = t0.x + C_DT * (C_ATTR * (g0.x - t0.x));
  o0.y = t0.y + C_DT * (C_ATTR * (g0.y - t0.y));
  o0.z = t0.z + C_DT * (C_ATTR * (g0.z - t0.z));
  o0.w = t0.w + C_DT * (C_ATTR * (g0.w - t0.w));
  o1.x = t1.x + C_DT * (C_ATTR * (g1.x - t1.x));
  o1.y = t1.y + C_DT * (C_ATTR * (g1.y - t1.y));
  o1.z = t1.z + C_DT * (C_ATTR * (g1.z - t1.z));
  o1.w = t1.w + C_DT * (C_ATTR * (g1.w - t1.w));
  *(float4*)(out + (size_t)idx * 8) = o0;
  *(float4*)(out + (size_t)idx * 8 + 4) = o1;
  const float v[8] = {t0.x, t0.y, t0.z, t0.w, t1.x, t1.y, t1.z, t1.w};
  unsigned short* Tb = T + (size_t)b * 16 * N + j;
  #pragma unroll
  for (int d = 0; d < 8; ++d) {
    Tb[(size_t)d * N]       = (unsigned short)f2bf(__sinf(v[d]));
    Tb[(size_t)(d + 8) * N] = (unsigned short)f2bf(__cosf(v[d]));
  }
}

// Each wave owns one 16-row i-tile of batch b and a j-chunk.
// P = (A.*cos(alpha)) x [sin|cos](theta)  (cols 0-7 s-part, 8-15 c-part)
// Q = (A.*sin(alpha)) x [sin|cos](theta)
// coupling(i,d) = (C/N) * ( c_i*(P[d] - Q[d+8]) - s_i*(P[d+8] + Q[d]) )
__global__ __launch_bounds__(256) void vk_main(
    const float* __restrict__ theta,
    const float* __restrict__ affinity,
    const float* __restrict__ alpha,
    const unsigned short* __restrict__ T,
    float* __restrict__ out,
    int N, int jsCnt, int jChunk) {
  const int jc = blockIdx.x % jsCnt;
  int t = blockIdx.x / jsCnt;
  const int nib = N >> 6;            // i-blocks of 64 rows
  const int ib = t % nib;
  const int b = t / nib;

  const int wave = threadIdx.x >> 6;
  const int lane = threadIdx.x & 63;
  const int itile = ib * 4 + wave;   // 16-row tile
  const int g = lane >> 4;           // k-group 0..3
  const int col = lane & 15;         // A row (M) / B col (N) index
  const int arow = itile * 16 + col;

  const float* __restrict__ Arow = affinity + ((size_t)b * N + arow) * (size_t)N;
  const float* __restrict__ Lrow = alpha    + ((size_t)b * N + arow) * (size_t)N;
  const unsigned short* __restrict__ Trow = T + ((size_t)b * 16 + col) * (size_t)N;

  f32x4 P = {0.f, 0.f, 0.f, 0.f};
  f32x4 Q = {0.f, 0.f, 0.f, 0.f};

  const int j0 = jc * jChunk;
  const int j1 = j0 + jChunk;
  #pragma unroll 4
  for (int jt = j0; jt < j1; jt += 32) {
    const int jl = jt + g * 8;       // this lane's 8 consecutive j's
    const float4 a0 = *(const float4*)(Arow + jl);
    const float4 a1 = *(const float4*)(Arow + jl + 4);
    const float4 l0 = *(const float4*)(Lrow + jl);
    const float4 l1 = *(const float4*)(Lrow + jl + 4);
    const short8 bf = *(const short8*)(Trow + jl);   // one 16B load

    short8 wc, ws;
    const float av[8] = {a0.x, a0.y, a0.z, a0.w, a1.x, a1.y, a1.z, a1.w};
    const float lv[8] = {l0.x, l0.y, l0.z, l0.w, l1.x, l1.y, l1.z, l1.w};
    #pragma unroll
    for (int k = 0; k < 8; ++k) {
      float sv = __sinf(lv[k]);
      float cv = __cosf(lv[k]);
      wc[k] = f2bf(av[k] * cv);
      ws[k] = f2bf(av[k] * sv);
    }
    P = __builtin_amdgcn_mfma_f32_16x16x32_bf16(wc, bf, P, 0, 0, 0);
    Q = __builtin_amdgcn_mfma_f32_16x16x32_bf16(ws, bf, Q, 0, 0, 0);
  }

  // C/D layout: col = lane&15, row = (lane>>4)*4 + reg  [m89]
  // lane col=d needs cols d+8 -> partner lane = lane ^ 8 (same g, same rows)
  float pc[4], qc[4];
  #pragma unroll
  for (int r = 0; r < 4; ++r) {
    pc[r] = __shfl_xor(P[r], 8, 64);
    qc[r] = __shfl_xor(Q[r], 8, 64);
  }
  if (col < 8) {
    const float sc = C_COUPLING / (float)N;
    #pragma unroll
    for (int r = 0; r < 4; ++r) {
      const int i = itile * 16 + g * 4 + r;
      const size_t oi = (((size_t)b * N + i) << 3) + col;
      const float thi = theta[oi];
      const float sv = __sinf(thi);
      const float cv = __cosf(thi);
      const float coup = sc * (cv * (P[r] - qc[r]) - sv * (pc[r] + Q[r]));
      unsafeAtomicAdd(out + oi, coup);
    }
  }
}

extern "C" void kernel_launch(void* const* d_in, const int* in_sizes, int n_in,
                              void* d_out, int out_size, void* d_ws, size_t ws_size,
                              hipStream_t stream) {
  const float* theta = (const float*)d_in[0];
  const float* gamma = (const float*)d_in[1];
  const float* aff   = (const float*)d_in[2];
  const float* alp   = (const float*)d_in[3];
  float* out = (float*)d_out;
  unsigned short* T = (unsigned short*)d_ws;   // B*16*N bf16 = 256 KB

  const long t0 = in_sizes[0];              // B*N*D (D=8)
  const long t2 = in_sizes[2];              // B*N*N
  const int N = (int)(8 * t2 / t0);
  const int B = (int)(t0 / ((long)N * 8));

  const int bn = B * N;
  vk_prep<<<dim3((bn + 255) / 256), dim3(256), 0, stream>>>(theta, gamma, out, T, N, bn);

  const int js = 16;                         // 2048 blocks -> 8 blocks/CU
  const int jChunk = N / js;
  dim3 grid(B * (N / 64) * js);
  vk_main<<<grid, dim3(256), 0, stream>>>(theta, aff, alp, T, out, N, js, jChunk);
}